// Round 1
// baseline (761.789 us; speedup 1.0000x reference)
//
#include <hip/hip_runtime.h>
#include <math.h>

#define MAX_WLEN 16
#define EMB 64
#define HID 256
#define MT 16                 // words per block
#define KTOT (HID + EMB)      // 320
#define LSTR (KTOT + 8)       // LDS row stride in floats (pad to de-phase banks)

__device__ __forceinline__ float sigm(float x) {
  return 1.0f / (1.0f + __expf(-x));
}

// Re-pack weights k-major: WT2[k][unit j][gate q] = W[g=q*256+j][k]
// k<256 -> W_hh, k>=256 -> W_ih. Also bias4[j][q] = b_ih[g]+b_hh[g].
__global__ __launch_bounds__(256) void prep_w(
    const float* __restrict__ W_ih, const float* __restrict__ W_hh,
    const float* __restrict__ b_ih, const float* __restrict__ b_hh,
    float* __restrict__ WT2, float* __restrict__ bias4) {
  const int j = threadIdx.x;   // unit 0..255
  const int k = blockIdx.x;    // 0..319
  float* dst = WT2 + ((size_t)(k * 256 + j)) * 4;
#pragma unroll
  for (int q = 0; q < 4; ++q) {
    const int g = q * 256 + j;
    dst[q] = (k < HID) ? W_hh[g * HID + k] : W_ih[g * EMB + (k - HID)];
  }
  if (k == 0) {
#pragma unroll
    for (int q = 0; q < 4; ++q) {
      const int g = q * 256 + j;
      bias4[j * 4 + q] = b_ih[g] + b_hh[g];
    }
  }
}

__global__ __launch_bounds__(256) void lstm_attn(
    const int* __restrict__ chars, const int* __restrict__ wordlens,
    const int* __restrict__ orig_idx, const float* __restrict__ emb_table,
    const float* __restrict__ attn_w, const float* __restrict__ h_init,
    const float* __restrict__ c_init, const float* __restrict__ WT2,
    const float* __restrict__ bias4, float* __restrict__ out) {
  __shared__ float in_lds[MT * LSTR];       // [m][k]: k<256 = h_{t-1}, k>=256 = x_t
  __shared__ int   chars_lds[MT * MAX_WLEN];
  __shared__ float part_lds[4 * MT];
  __shared__ float wgt_lds[MT];
  __shared__ int   len_lds[MT];

  const int j  = threadIdx.x;               // hidden unit owned by this thread
  const int w0 = blockIdx.x * MT;

  chars_lds[j] = chars[w0 * MAX_WLEN + j];  // 256 ints = 16 words x 16 slots
  if (j < MT) len_lds[j] = wordlens[w0 + j];

  const float aw   = attn_w[j];
  const float hini = h_init[j];
  const float cini = c_init[j];
  float c_reg[MT], res_acc[MT], h_new[MT];
#pragma unroll
  for (int m = 0; m < MT; ++m) { c_reg[m] = cini; res_acc[m] = 0.0f; h_new[m] = hini; }
#pragma unroll
  for (int m = 0; m < MT; ++m) in_lds[m * LSTR + j] = hini;
  __syncthreads();

  int steps = 0;
#pragma unroll
  for (int m = 0; m < MT; ++m) steps = max(steps, len_lds[m]);  // sorted desc, but be robust

  const float4 bias = ((const float4*)bias4)[j];
  const float4* __restrict__ Wp = ((const float4*)WT2) + j;
  const int lane = j & 63;
  const int wv   = j >> 6;

  for (int t = 0; t < steps; ++t) {
    // stage x_t = emb_table[chars[w][t]] into in_lds[m][256..319]
    {
      const int m = j >> 4, eg = j & 15;
      const int ch = chars_lds[m * MAX_WLEN + t];
      const float4 e = ((const float4*)emb_table)[ch * 16 + eg];
      *(float4*)&in_lds[m * LSTR + HID + eg * 4] = e;
    }
    if (t > 0) {
#pragma unroll
      for (int m = 0; m < MT; ++m) in_lds[m * LSTR + j] = h_new[m];
    }
    __syncthreads();

    // gates GEMM: acc[m] = bias + [h|x] @ W^T  (thread j owns gate rows j,256+j,512+j,768+j)
    float4 acc[MT];
#pragma unroll
    for (int m = 0; m < MT; ++m) acc[m] = bias;

#pragma unroll 2
    for (int k = 0; k < KTOT; k += 4) {
      const float4 wv0 = Wp[(size_t)(k + 0) * 256];
      const float4 wv1 = Wp[(size_t)(k + 1) * 256];
      const float4 wv2 = Wp[(size_t)(k + 2) * 256];
      const float4 wv3 = Wp[(size_t)(k + 3) * 256];
#pragma unroll
      for (int m = 0; m < MT; ++m) {
        const float4 in4 = *(const float4*)&in_lds[m * LSTR + k];
        acc[m].x = fmaf(in4.x, wv0.x, fmaf(in4.y, wv1.x, fmaf(in4.z, wv2.x, fmaf(in4.w, wv3.x, acc[m].x))));
        acc[m].y = fmaf(in4.x, wv0.y, fmaf(in4.y, wv1.y, fmaf(in4.z, wv2.y, fmaf(in4.w, wv3.y, acc[m].y))));
        acc[m].z = fmaf(in4.x, wv0.z, fmaf(in4.y, wv1.z, fmaf(in4.z, wv2.z, fmaf(in4.w, wv3.z, acc[m].z))));
        acc[m].w = fmaf(in4.x, wv0.w, fmaf(in4.y, wv1.w, fmaf(in4.z, wv2.w, fmaf(in4.w, wv3.w, acc[m].w))));
      }
    }

    // LSTM cell (torch gate order i,f,g,o)
#pragma unroll
    for (int m = 0; m < MT; ++m) {
      const float ig = sigm(acc[m].x);
      const float fg = sigm(acc[m].y);
      const float gg = tanhf(acc[m].z);
      const float og = sigm(acc[m].w);
      const float cc = fg * c_reg[m] + ig * gg;
      c_reg[m] = cc;
      h_new[m] = og * tanhf(cc);
    }

    // fused masked sigmoid-attention: dot(h_t, attn_w) reduced across 256 threads
#pragma unroll
    for (int m = 0; m < MT; ++m) {
      float p = h_new[m] * aw;
      p += __shfl_xor(p, 1);
      p += __shfl_xor(p, 2);
      p += __shfl_xor(p, 4);
      p += __shfl_xor(p, 8);
      p += __shfl_xor(p, 16);
      p += __shfl_xor(p, 32);
      if (lane == 0) part_lds[wv * MT + m] = p;
    }
    __syncthreads();
    if (j < MT) {
      const float s = part_lds[j] + part_lds[MT + j] + part_lds[2 * MT + j] + part_lds[3 * MT + j];
      wgt_lds[j] = (t < len_lds[j]) ? sigm(s) : 0.0f;   // pad mask
    }
    __syncthreads();
#pragma unroll
    for (int m = 0; m < MT; ++m) res_acc[m] += wgt_lds[m] * h_new[m];
  }

  // tensor_unsort + write (coalesced per word row)
#pragma unroll
  for (int m = 0; m < MT; ++m) {
    out[(size_t)orig_idx[w0 + m] * HID + j] = res_acc[m];
  }
}

extern "C" void kernel_launch(void* const* d_in, const int* in_sizes, int n_in,
                              void* d_out, int out_size, void* d_ws, size_t ws_size,
                              hipStream_t stream) {
  const int*   chars    = (const int*)d_in[0];
  const int*   wordlens = (const int*)d_in[1];
  const int*   orig_idx = (const int*)d_in[2];
  const float* emb      = (const float*)d_in[3];
  const float* W_ih     = (const float*)d_in[4];
  const float* W_hh     = (const float*)d_in[5];
  const float* b_ih     = (const float*)d_in[6];
  const float* b_hh     = (const float*)d_in[7];
  const float* attn_w   = (const float*)d_in[8];
  const float* h_init   = (const float*)d_in[9];
  const float* c_init   = (const float*)d_in[10];
  float* out = (float*)d_out;

  float* WT2   = (float*)d_ws;            // 320*1024 floats = 1.25 MiB
  float* bias4 = WT2 + 320 * 1024;        // 1024 floats
  if (ws_size < (size_t)(320 * 1024 + 1024) * sizeof(float)) return;

  hipLaunchKernelGGL(prep_w, dim3(KTOT), dim3(256), 0, stream,
                     W_ih, W_hh, b_ih, b_hh, WT2, bias4);
  hipLaunchKernelGGL(lstm_attn, dim3(8192 / MT), dim3(256), 0, stream,
                     chars, wordlens, orig_idx, emb, attn_w, h_init, c_init,
                     WT2, bias4, out);
}

// Round 2
// 289.272 us; speedup vs baseline: 2.6335x; 2.6335x over previous
//
#include <hip/hip_runtime.h>
#include <math.h>

#define HID 256
#define EMB 64
#define KTOT 320           // HID + EMB
#define MT 32              // words per block
#define NWORDS 8192
#define NBLK (NWORDS / MT) // 256 blocks = 1 per CU
#define THREADS 512
#define KT 10              // k-tiles of 32
#define XSTR 328           // X row stride in f16 (320 + 8 pad -> de-phased banks)
#define GSTR 40            // gates row stride in f16 (32 m + 8 pad), 80B = 16B-aligned rows

typedef _Float16 f16;
typedef _Float16 f16x8 __attribute__((ext_vector_type(8)));
typedef _Float16 f16x4 __attribute__((ext_vector_type(4)));
typedef float f32x4 __attribute__((ext_vector_type(4)));

__device__ __forceinline__ float sigm(float x) { return 1.0f / (1.0f + __expf(-x)); }

// Wfrag[(kt*1024 + g)*32 + (k&31)] = f16(Wcat[g][k]),  Wcat[g] = [W_hh[g] | W_ih[g]]
// -> per (kt, n-tile) a wave's B-fragment load is 1KB fully coalesced.
__global__ __launch_bounds__(KTOT) void prep_w(const float* __restrict__ W_ih,
                                               const float* __restrict__ W_hh,
                                               const float* __restrict__ b_ih,
                                               const float* __restrict__ b_hh,
                                               f16* __restrict__ Wfrag,
                                               float* __restrict__ bias) {
  const int g = blockIdx.x;   // 0..1023 (gate row, torch order i,f,g,o blocks of 256)
  const int k = threadIdx.x;  // 0..319
  const float w = (k < HID) ? W_hh[g * HID + k] : W_ih[g * EMB + (k - HID)];
  const int kt = k >> 5;
  Wfrag[(size_t)(kt * 1024 + g) * 32 + (k & 31)] = (f16)w;
  if (k == 0) bias[g] = b_ih[g] + b_hh[g];
}

__global__ __launch_bounds__(THREADS, 2) void lstm_mfma(
    const int* __restrict__ chars, const int* __restrict__ wordlens,
    const int* __restrict__ orig_idx, const float* __restrict__ emb_table,
    const float* __restrict__ attn_w, const float* __restrict__ h_init,
    const float* __restrict__ c_init, const f16* __restrict__ Wfrag,
    const float* __restrict__ bias, float* __restrict__ out) {
  __shared__ __align__(16) f16 Xs[MT * XSTR];        // [m][k]: k<256 = h_{t-1}, k>=256 = x_t
  __shared__ __align__(16) f16 gatesS[1024 * GSTR];  // [g][m] pre-activation gates (+bias)
  __shared__ int   chars_s[MT * 16];
  __shared__ float part_s[8 * 16];
  __shared__ float wgt_s[MT];
  __shared__ int   len_s[MT];
  __shared__ int   oidx_s[MT];

  const int tid  = threadIdx.x;
  const int w0   = blockIdx.x * MT;
  const int j    = tid & 255;   // hidden unit owned in cell phase
  const int mh   = tid >> 8;    // which half of the 32 words (0/1)
  const int lane = tid & 63;
  const int wv   = tid >> 6;    // wave 0..7, owns n-slice [wv*128, wv*128+128)
  const int r15  = lane & 15, c4 = lane >> 4;
  const int n0   = wv * 128;

  chars_s[tid] = chars[w0 * 16 + tid];
  if (tid < MT) { len_s[tid] = wordlens[w0 + tid]; oidx_s[tid] = orig_idx[w0 + tid]; }

  const float aw   = attn_w[j];
  const float cini = c_init[j];
  const f16   hini = (f16)h_init[j];
#pragma unroll
  for (int mm = 0; mm < 16; ++mm) Xs[(mh * 16 + mm) * XSTR + j] = hini;

  float c_reg[16], res_acc[16], h_new[16];
#pragma unroll
  for (int mm = 0; mm < 16; ++mm) { c_reg[mm] = cini; res_acc[mm] = 0.0f; h_new[mm] = 0.0f; }

  float biasr[8];
#pragma unroll
  for (int ntl = 0; ntl < 8; ++ntl) biasr[ntl] = bias[n0 + ntl * 16 + r15];

  __syncthreads();
  int steps = 1;
#pragma unroll
  for (int m = 0; m < MT; ++m) steps = max(steps, len_s[m]);  // sorted desc globally

  for (int t = 0; t < steps; ++t) {
    // ---- stage x_t = f16(emb[chars[w][t]]) into Xs[m][256..319]
    {
      const int m = tid >> 4, eg = tid & 15;
      const int ch = chars_s[m * 16 + t];
      const float4 e = ((const float4*)emb_table)[ch * 16 + eg];
      f16x4 ev = { (f16)e.x, (f16)e.y, (f16)e.z, (f16)e.w };
      *(f16x4*)&Xs[m * XSTR + HID + eg * 4] = ev;
    }
    __syncthreads();

    // ---- gates GEMM via MFMA: gates[m][g] = bias[g] + X[m][:] . Wcat[g][:]
    f32x4 acc[8][2];
#pragma unroll
    for (int ntl = 0; ntl < 8; ++ntl) {
      const f32x4 b4 = { biasr[ntl], biasr[ntl], biasr[ntl], biasr[ntl] };
      acc[ntl][0] = b4;
      acc[ntl][1] = b4;
    }

#pragma unroll 2
    for (int kt = 0; kt < KT; ++kt) {
      const f16x8 a0 = *(const f16x8*)&Xs[r15 * XSTR + kt * 32 + c4 * 8];
      const f16x8 a1 = *(const f16x8*)&Xs[(16 + r15) * XSTR + kt * 32 + c4 * 8];
      const f16x8* __restrict__ Wp = (const f16x8*)(Wfrag + (size_t)kt * 1024 * 32);
#pragma unroll
      for (int ntl = 0; ntl < 8; ++ntl) {
        const f16x8 b = Wp[(size_t)(n0 + ntl * 16 + r15) * 4 + c4];
        acc[ntl][0] = __builtin_amdgcn_mfma_f32_16x16x32_f16(a0, b, acc[ntl][0], 0, 0, 0);
        acc[ntl][1] = __builtin_amdgcn_mfma_f32_16x16x32_f16(a1, b, acc[ntl][1], 0, 0, 0);
      }
    }

    // D layout: col g = n0+ntl*16+(lane&15), row m = mt*16 + (lane>>4)*4 + r
#pragma unroll
    for (int ntl = 0; ntl < 8; ++ntl) {
      const int g = n0 + ntl * 16 + r15;
#pragma unroll
      for (int mt = 0; mt < 2; ++mt) {
        const f32x4 v = acc[ntl][mt];
        f16x4 hv = { (f16)v.x, (f16)v.y, (f16)v.z, (f16)v.w };
        *(f16x4*)&gatesS[g * GSTR + mt * 16 + c4 * 4] = hv;
      }
    }
    __syncthreads();

    // ---- LSTM cell (thread j owns unit j, words mh*16..mh*16+15)
    f16x8 gA[4], gB[4];
#pragma unroll
    for (int q = 0; q < 4; ++q) {
      const int g = q * 256 + j;
      gA[q] = *(const f16x8*)&gatesS[g * GSTR + mh * 16];
      gB[q] = *(const f16x8*)&gatesS[g * GSTR + mh * 16 + 8];
    }
#pragma unroll
    for (int mm = 0; mm < 16; ++mm) {
      const float gi = (float)(mm < 8 ? gA[0][mm & 7] : gB[0][mm & 7]);
      const float gf = (float)(mm < 8 ? gA[1][mm & 7] : gB[1][mm & 7]);
      const float gg = (float)(mm < 8 ? gA[2][mm & 7] : gB[2][mm & 7]);
      const float go = (float)(mm < 8 ? gA[3][mm & 7] : gB[3][mm & 7]);
      const float ig = sigm(gi);
      const float fg = sigm(gf);
      const float gv = tanhf(gg);
      const float og = sigm(go);
      const float cc = fg * c_reg[mm] + ig * gv;
      c_reg[mm] = cc;
      h_new[mm] = og * tanhf(cc);
    }
    // h_t -> Xs for next step (region read by MFMA only after next barrier)
#pragma unroll
    for (int mm = 0; mm < 16; ++mm)
      Xs[(mh * 16 + mm) * XSTR + j] = (f16)h_new[mm];

    // ---- fused masked sigmoid attention
#pragma unroll
    for (int mm = 0; mm < 16; ++mm) {
      float p = h_new[mm] * aw;
      p += __shfl_xor(p, 1);  p += __shfl_xor(p, 2);  p += __shfl_xor(p, 4);
      p += __shfl_xor(p, 8);  p += __shfl_xor(p, 16); p += __shfl_xor(p, 32);
      if (lane == 0) part_s[wv * 16 + mm] = p;
    }
    __syncthreads();
    if (tid < MT) {
      const int m = tid;
      const int base = (m >> 4) * 4;
      const float s = part_s[(base + 0) * 16 + (m & 15)] + part_s[(base + 1) * 16 + (m & 15)]
                    + part_s[(base + 2) * 16 + (m & 15)] + part_s[(base + 3) * 16 + (m & 15)];
      wgt_s[m] = (t < len_s[m]) ? sigm(s) : 0.0f;
    }
    __syncthreads();
#pragma unroll
    for (int mm = 0; mm < 16; ++mm)
      res_acc[mm] += wgt_s[mh * 16 + mm] * h_new[mm];
  }

  // ---- tensor_unsort + write
#pragma unroll
  for (int mm = 0; mm < 16; ++mm)
    out[(size_t)oidx_s[mh * 16 + mm] * HID + j] = res_acc[mm];
}

extern "C" void kernel_launch(void* const* d_in, const int* in_sizes, int n_in,
                              void* d_out, int out_size, void* d_ws, size_t ws_size,
                              hipStream_t stream) {
  const int*   chars    = (const int*)d_in[0];
  const int*   wordlens = (const int*)d_in[1];
  const int*   orig_idx = (const int*)d_in[2];
  const float* emb      = (const float*)d_in[3];
  const float* W_ih     = (const float*)d_in[4];
  const float* W_hh     = (const float*)d_in[5];
  const float* b_ih     = (const float*)d_in[6];
  const float* b_hh     = (const float*)d_in[7];
  const float* attn_w   = (const float*)d_in[8];
  const float* h_init   = (const float*)d_in[9];
  const float* c_init   = (const float*)d_in[10];
  float* out = (float*)d_out;

  f16*   Wfrag = (f16*)d_ws;                       // 1024*320 f16 = 640 KiB
  float* bias  = (float*)((char*)d_ws + (size_t)1024 * 320 * sizeof(f16));
  if (ws_size < (size_t)1024 * 320 * sizeof(f16) + 1024 * sizeof(float)) return;

  hipLaunchKernelGGL(prep_w, dim3(1024), dim3(KTOT), 0, stream,
                     W_ih, W_hh, b_ih, b_hh, Wfrag, bias);
  hipLaunchKernelGGL(lstm_mfma, dim3(NBLK), dim3(THREADS), 0, stream,
                     chars, wordlens, orig_idx, emb, attn_w, h_init, c_init,
                     Wfrag, bias, out);
}